// Round 4
// baseline (277.533 us; speedup 1.0000x reference)
//
#include <hip/hip_runtime.h>

typedef float v2f __attribute__((ext_vector_type(2)));

#define NT 512   // threads per block
#define NR 16    // v2f amplitudes per thread (4-bit register window)

// SU(2) rotation on a register pair: U = [[a, b], [-conj(b), conj(a)]]
__device__ __forceinline__ void rot2(v2f& x, v2f& y, v2f aa, v2f an, v2f bb, v2f bn) {
  v2f xs = __builtin_shufflevector(x, x, 1, 0);
  v2f ys = __builtin_shufflevector(y, y, 1, 0);
  v2f n0 = aa * x + an * xs + bb * y + bn * ys;
  v2f n1 = aa * y - an * ys + bn * xs - bb * x;
  x = n0;
  y = n1;
}

#define ROT(T, G)                                                              \
  do {                                                                         \
    const float4 u = Utab[G];                                                  \
    const v2f aa = {u.x, u.x}, an = {-u.y, u.y};                               \
    const v2f bb = {u.z, u.z}, bn = {-u.w, u.w};                               \
    _Pragma("unroll") for (int v = 0; v < NR; ++v) if (!((v >> (T)) & 1))      \
        rot2(s[v], s[v | (1 << (T))], aa, an, bb, bn);                         \
  } while (0)

// CNOT, both bits in window: compile-time register swap (zero instructions).
#define CNOTW(C, T)                                                            \
  do {                                                                         \
    _Pragma("unroll") for (int v = 0; v < NR; ++v)                             \
        if (((v >> (C)) & 1) && !((v >> (T)) & 1)) {                           \
      v2f tmp = s[v];                                                          \
      s[v] = s[v | (1 << (T))];                                                \
      s[v | (1 << (T))] = tmp;                                                 \
    }                                                                          \
  } while (0)

// Window maps: 13-bit local element index c from (t[8:0], reg v[3:0]).
#define MAP_A1(t, v) (((v) << 9) | (t))                               // reg = c12..9
#define MAP_A2(t, v) ((((t) >> 6) << 10) | ((v) << 6) | ((t) & 63))   // reg = c9..6
#define MAP_A3(t, v) ((((t) >> 3) << 7) | ((v) << 3) | ((t) & 7))     // reg = c6..3
#define MAP_A4(t, v) (((t) << 4) | (v))                               // reg = c3..0
#define MAP_B2(t, v) ((((t) >> 2) << 6) | ((v) << 2) | ((t) & 3))     // reg = c5..2
#define MAP_B3(t, v) ((((t) >> 1) << 5) | ((v) << 1) | ((t) & 1))     // reg = c4..1

// Per-edge additive LDS byte-address layouts (bit placements, each a
// bijection c[12:0] -> A[15:3]). Chosen so BOTH endpoint maps of the edge
// fold to base(t) + compile-time immediate, with bank bits A[6:3] drawn
// from lane-varying bits of both sides.
#define AE1(c) (((((c)>>2)&0xF)<<3) | (((c)&3)<<7) | ((((c)>>6)&7)<<9) | ((((c)>>9)&0xF)<<12))
#define AE2(c) ((((c)&7)<<3) | ((((c)>>9)&1)<<6) | ((((c)>>3)&0xF)<<7) | ((((c)>>7)&3)<<11) | ((((c)>>10)&7)<<13))
#define AE3(c) ((((c)&1)<<3) | ((((c)>>7)&7)<<4) | ((((c)>>1)&3)<<7) | ((((c)>>3)&0xF)<<9) | ((((c)>>10)&7)<<13))
#define AE4(c) (((((c)>>3)&1)<<3) | ((((c)>>4)&3)<<4) | ((((c)>>9)&1)<<6) | (((c)&3)<<7) | ((((c)>>2)&1)<<9) | ((((c)>>6)&7)<<10) | ((((c)>>10)&7)<<13))
#define AF1(c) (((((c)>>4)&1)<<3) | ((((c)>>7)&7)<<4) | (((c)&7)<<7) | ((((c)>>3)&1)<<10) | ((((c)>>5)&3)<<11) | ((((c)>>10)&7)<<13))
#define AF2(c) (((((c)>>1)&1)<<3) | ((((c)>>7)&7)<<4) | (((c)&1)<<7) | ((((c)>>2)&1)<<8) | ((((c)>>3)&0xF)<<9) | ((((c)>>10)&7)<<13))
#define AF3(c) (((((c)>>6)&0xF)<<3) | (((c)&0x3F)<<7) | ((((c)>>10)&7)<<13))
#define AE5(c) ((((c)&1)<<3) | ((((c)>>1)&7)<<4) | ((((c)>>4)&7)<<7) | ((((c)>>7)&7)<<10) | ((((c)>>10)&7)<<13))
#define AF0(c) (((((c)>>4)&0xF)<<3) | ((((c)>>8)&3)<<7) | (((c)&0xF)<<9) | ((((c)>>10)&7)<<13))

#define LDSB(a) (*(v2f*)((char*)lds2 + (a)))

#define RW(AD, MW) _Pragma("unroll") for (int r = 0; r < NR; ++r) LDSB(AD(MW(tid, r))) = s[r]
#define RR(AD, MR) _Pragma("unroll") for (int v = 0; v < NR; ++v) s[v] = LDSB(AD(MR(tid, v)))

// Wave-local remap (both maps keep c[12:10] -> A[15:13] = wave id): no barrier.
#define REMAP_L2(AD, MW, MR)   do { RW(AD, MW); RR(AD, MR); } while (0)
// Cross-wave write (scatters across regions): barrier both sides.
#define REMAP_BWB2(AD, MW, MR) do { __syncthreads(); RW(AD, MW); __syncthreads(); RR(AD, MR); } while (0)
// Own-region write, cross-wave read: barrier between.
#define REMAP_WB2(AD, MW, MR)  do { RW(AD, MW); __syncthreads(); RR(AD, MR); } while (0)

// ---------------------------------------------------------------------------
// Fused U = RZ @ RY @ RX per (layer, wire): (alpha_re, alpha_im, beta_re, beta_im)
__global__ void k_setup(const float* __restrict__ params, float4* __restrict__ Utab) {
  int g = threadIdx.x;
  if (g < 64) {
    float a = params[g * 3 + 0] * 0.5f;
    float b = params[g * 3 + 1] * 0.5f;
    float c = params[g * 3 + 2] * 0.5f;
    float sa, ca, sb, cb, sc, cc;
    sincosf(a, &sa, &ca);
    sincosf(b, &sb, &cb);
    sincosf(c, &sc, &cc);
    float X = cb * ca, Y = sb * sa;
    float Xp = -sb * ca, Yp = -cb * sa;
    Utab[g] = make_float4(cc * X + sc * Y, cc * Y - sc * X,
                          cc * Xp + sc * Yp, cc * Yp - sc * Xp);
  }
}

// ---------------------------------------------------------------------------
// Pass A: local wires 0..12 (orig bits 15..3); wire q <-> local bit 12-q.
__global__ __launch_bounds__(NT, 2) void k_passA(const float* __restrict__ in,
                                                 const float4* __restrict__ Utab,
                                                 v2f* __restrict__ st) {
  __shared__ v2f lds2[8192];
  const int tid = threadIdx.x;
  const int g = (blockIdx.x >> 3) & 7;
  const int b = ((blockIdx.x >> 6) << 3) | (blockIdx.x & 7);
  const float* base = in + (size_t)b * 65536;

  v2f s[NR];
#pragma unroll
  for (int v = 0; v < NR; ++v) {
    float re = base[(v << 12) + (tid << 3) + g];
    s[v] = v2f{re, 0.0f};
  }

#pragma unroll
  for (int l = 0; l < 4; ++l) {
    // W1: reg bits c12..9 = wires 0..3 (T = 3-q)
    ROT(3, l * 16 + 0); ROT(2, l * 16 + 1); ROT(1, l * 16 + 2); ROT(0, l * 16 + 3);
    CNOTW(3, 2); CNOTW(2, 1); CNOTW(1, 0);       // C_l (0,1),(1,2),(2,3)
    REMAP_BWB2(AE1, MAP_A1, MAP_A2);
    // W2: reg bits c9..6 = wires 3..6; rotations on 4,5,6
    ROT(2, l * 16 + 4); ROT(1, l * 16 + 5); ROT(0, l * 16 + 6);
    CNOTW(3, 2); CNOTW(2, 1); CNOTW(1, 0);       // C_l (3,4),(4,5),(5,6)
    REMAP_L2(AE2, MAP_A2, MAP_A3);
    // W3: reg bits c6..3 = wires 6..9; rotations on 7,8,9
    ROT(2, l * 16 + 7); ROT(1, l * 16 + 8); ROT(0, l * 16 + 9);
    CNOTW(3, 2); CNOTW(2, 1); CNOTW(1, 0);       // C_l (6,7),(7,8),(8,9)
    if (l < 3) {
      REMAP_L2(AE3, MAP_A3, MAP_A4);
      // W4: reg bits c3..0 = wires 9..12; staircase tail
      ROT(2, l * 16 + 10);
      if (l <= 1) ROT(1, l * 16 + 11);
      if (l == 0) ROT(0, l * 16 + 12);
      CNOTW(3, 2);
      if (l <= 1) CNOTW(2, 1);
      if (l == 0) CNOTW(1, 0);
      REMAP_WB2(AE4, MAP_A4, MAP_A1);
    }
  }

  // Exit: write A3 arrangement via edge-E5 layout, then b128 coalesced reads.
  RW(AE5, MAP_A3);
  __syncthreads();
  float4* outp = (float4*)(st + (size_t)(b * 8 + g) * 8192);
#pragma unroll
  for (int k = 0; k < 8; ++k) {
    // element pair c = (k<<10)|(tid<<1), c+1 -> adjacent bytes under AE5
    int a = ((tid & 7) << 4) | (((tid >> 3) & 7) << 7) | (((tid >> 6) & 7) << 10) | (k << 13);
    outp[(k << 9) + tid] = *(float4*)((char*)lds2 + a);
  }
}

// ---------------------------------------------------------------------------
// Pass B: local wires 3..15 (orig bits 12..0); wire q <-> local bit 15-q.
__global__ __launch_bounds__(NT, 2) void k_passB(const v2f* __restrict__ st,
                                                 const float4* __restrict__ Utab,
                                                 float* __restrict__ partials) {
  __shared__ v2f lds2[8192];
  const int tid = threadIdx.x;
  const int b = blockIdx.x >> 3;
  const int h = blockIdx.x & 7;  // orig bits 15..13
  const float4* base4 = (const float4*)(st + (size_t)b * 65536);

  // Coalesced float4 load; elements c0=(tid<<4)|k, c1=c0|8 via F0 layout.
  // Wave-local (c[12:10]=tid[8:6] -> A[15:13]); no barrier needed.
#pragma unroll
  for (int k = 0; k < 8; ++k) {
    float4 val = base4[(k << 12) + (h << 9) + tid];
    int t4 = ((tid & 15) << 3) | (((tid >> 4) & 3) << 7) | (((tid >> 6) & 7) << 13);
    LDSB(t4 | (k << 9)) = v2f{val.x, val.y};
    LDSB(t4 | (k << 9) | (1 << 12)) = v2f{val.z, val.w};
  }
  v2f s[NR];
  RR(AF0, MAP_A4);

  // P0: reg bits c3..0 (T = bit)
  ROT(2, 13); ROT(1, 14); ROT(0, 15);          // R0 wires 13,14,15
  CNOTW(3, 2); CNOTW(2, 1); CNOTW(1, 0);       // C0 (12,13),(13,14),(14,15)
  ROT(3, 28); ROT(2, 29); ROT(1, 30); ROT(0, 31);  // R1 wires 12..15
  REMAP_L2(AF1, MAP_A4, MAP_A3);
  // P1: reg bits c6..3 (T = bit-3)
  CNOTW(1, 0);      // C1 (11,12)
  ROT(1, 43);       // R2 wire 11
  CNOTW(2, 1);      // C2 (10,11)
  ROT(2, 58);       // R3 wire 10
  CNOTW(3, 2);      // C3 (9,10)
  REMAP_L2(AF2, MAP_A3, MAP_B2);
  // P2: reg bits c5..2 (T = bit-2)
  CNOTW(1, 0);      // C1 (12,13)
  ROT(1, 44);       // R2 wire 12
  CNOTW(2, 1);      // C2 (11,12)
  ROT(2, 59);       // R3 wire 11
  CNOTW(3, 2);      // C3 (10,11)
  REMAP_L2(AF3, MAP_B2, MAP_B3);
  // P3: reg bits c4..1 (T = bit-1)
  CNOTW(1, 0);      // C1 (13,14)
  ROT(1, 45);       // R2 wire 13
  CNOTW(2, 1);      // C2 (12,13)
  ROT(2, 60);       // R3 wire 12
  CNOTW(3, 2);      // C3 (11,12)
  REMAP_L2(AF3, MAP_B3, MAP_A4);
  // P4: reg bits c3..0 (T = bit)
  CNOTW(1, 0);                 // C1 (14,15)
  ROT(1, 46); ROT(0, 47);      // R2 wires 14,15
  CNOTW(2, 1); CNOTW(1, 0);    // C2 (13,14),(14,15)
  ROT(2, 61); ROT(1, 62); ROT(0, 63);  // R3 wires 13,14,15
  CNOTW(3, 2); CNOTW(2, 1); CNOTW(1, 0);  // C3 (12,13),(13,14),(14,15)

  // Epilogue (A4 arrangement): c = (t<<4)|v; v bits 3..0 = wires 12..15,
  // t bits 8..0 = wires 3..11 (wire q <-> t bit 11-q).
  float P = 0.f, f12 = 0.f, f13 = 0.f, f14 = 0.f, f15 = 0.f;
#pragma unroll
  for (int v = 0; v < NR; ++v) {
    float p = s[v][0] * s[v][0] + s[v][1] * s[v][1];
    P += p;
    f12 += ((v >> 3) & 1) ? -p : p;
    f13 += ((v >> 2) & 1) ? -p : p;
    f14 += ((v >> 1) & 1) ? -p : p;
    f15 += ((v >> 0) & 1) ? -p : p;
  }
  float vals[14];
  vals[0] = P;
#pragma unroll
  for (int q = 3; q <= 11; ++q)
    vals[q - 2] = ((tid >> (11 - q)) & 1) ? -P : P;
  vals[10] = f12; vals[11] = f13; vals[12] = f14; vals[13] = f15;

  const int lane = tid & 63, w = tid >> 6;
#pragma unroll
  for (int q = 0; q < 14; ++q) {
    float x = vals[q];
#pragma unroll
    for (int m = 1; m < 64; m <<= 1) x += __shfl_xor(x, m, 64);
    vals[q] = x;
  }
  // red[] lives in wave-0's LDS region -> sync all waves' prior reads.
  __syncthreads();
  float* red = (float*)lds2;
  if (lane == 0) {
#pragma unroll
    for (int q = 0; q < 14; ++q) red[q * 8 + w] = vals[q];
  }
  __syncthreads();
  if (tid < 14) {
    float F = 0.f;
#pragma unroll
    for (int ww = 0; ww < 8; ++ww) F += red[tid * 8 + ww];
    float* pt = partials + (size_t)blockIdx.x * 16;
    if (tid == 0) {
      pt[0] = (h & 4) ? -F : F;  // wire 0 <-> h bit 2
      pt[1] = (h & 2) ? -F : F;  // wire 1
      pt[2] = (h & 1) ? -F : F;  // wire 2
    } else {
      pt[tid + 2] = F;           // tid 1..9 -> wires 3..11; 10..13 -> 12..15
    }
  }
}

// ---------------------------------------------------------------------------
__global__ void k_head(const float* __restrict__ partials, const float* __restrict__ w,
                       const float* __restrict__ bh, float* __restrict__ out) {
  int b = threadIdx.x;  // 256 threads
  float acc = bh[0];
  for (int q = 0; q < 16; ++q) {
    float F = 0.f;
    for (int hh = 0; hh < 8; ++hh) F += partials[(size_t)(b * 8 + hh) * 16 + q];
    acc += w[q] * F;
  }
  out[b] = acc;
}

// ---------------------------------------------------------------------------
extern "C" void kernel_launch(void* const* d_in, const int* in_sizes, int n_in,
                              void* d_out, int out_size, void* d_ws, size_t ws_size,
                              hipStream_t stream) {
  const float* state  = (const float*)d_in[0];
  const float* params = (const float*)d_in[1];
  const float* w_head = (const float*)d_in[2];
  const float* b_head = (const float*)d_in[3];
  float* out = (float*)d_out;

  char* ws = (char*)d_ws;
  v2f* st = (v2f*)ws;                                       // 128 MB
  float4* Utab = (float4*)(ws + (size_t)134217728);         // 1 KB
  float* partials = (float*)(ws + (size_t)134217728 + 1024);

  k_setup<<<1, 64, 0, stream>>>(params, Utab);
  k_passA<<<dim3(2048), dim3(NT), 0, stream>>>(state, Utab, st);
  k_passB<<<dim3(2048), dim3(NT), 0, stream>>>(st, Utab, partials);
  k_head<<<1, 256, 0, stream>>>(partials, w_head, b_head, out);
}

// Round 5
// 250.738 us; speedup vs baseline: 1.1069x; 1.1069x over previous
//
#include <hip/hip_runtime.h>

typedef float v2f __attribute__((ext_vector_type(2)));

#define NT 512   // threads per block
#define NR 16    // v2f amplitudes per thread (4-bit register window)

// ---------------------------------------------------------------------------
// LDS swizzle: l ^ ((l>>5)&31)  (round-3 verified: ~1 extra cyc/b64 = free).
__device__ __forceinline__ int swz(int l) { return l ^ ((l >> 5) & 31); }

// Packed f32 (VOP3P) via inline asm — probe: is v_pk_fma_f32 2x FLOP rate?
__device__ __forceinline__ v2f pk_mul(v2f a, v2f b) {
  v2f d;
  asm("v_pk_mul_f32 %0, %1, %2" : "=v"(d) : "v"(a), "v"(b));
  return d;
}
__device__ __forceinline__ v2f pk_fma(v2f a, v2f b, v2f c) {
  v2f d;
  asm("v_pk_fma_f32 %0, %1, %2, %3" : "=v"(d) : "v"(a), "v"(b), "v"(c));
  return d;
}

// SU(2) rotation on a register pair: U = [[a, b], [-conj(b), conj(a)]]
//   n0 = a*x + b*y ; n1 = -conj(b)*x + conj(a)*y   (complex, packed as v2f)
// All signs folded into pre-negated constant vectors (asm has no modifiers).
__device__ __forceinline__ void rot2(v2f& x, v2f& y, v2f aa, v2f an, v2f nan_,
                                     v2f bb, v2f nbb, v2f bn) {
  v2f xs = __builtin_shufflevector(x, x, 1, 0);
  v2f ys = __builtin_shufflevector(y, y, 1, 0);
  v2f n0 = pk_fma(bn, ys, pk_fma(bb, y, pk_fma(an, xs, pk_mul(aa, x))));
  v2f n1 = pk_fma(nbb, x, pk_fma(bn, xs, pk_fma(nan_, ys, pk_mul(aa, y))));
  x = n0;
  y = n1;
}

#define ROT(T, G)                                                              \
  do {                                                                         \
    const float4 u = Utab[G];                                                  \
    const v2f aa = {u.x, u.x}, an = {-u.y, u.y}, nan_ = {u.y, -u.y};           \
    const v2f bb = {u.z, u.z}, nbb = {-u.z, -u.z}, bn = {-u.w, u.w};           \
    _Pragma("unroll") for (int v = 0; v < NR; ++v) if (!((v >> (T)) & 1))      \
        rot2(s[v], s[v | (1 << (T))], aa, an, nan_, bb, nbb, bn);              \
  } while (0)

// CNOT, both bits in window: compile-time register swap (zero instructions).
#define CNOTW(C, T)                                                            \
  do {                                                                         \
    _Pragma("unroll") for (int v = 0; v < NR; ++v)                             \
        if (((v >> (C)) & 1) && !((v >> (T)) & 1)) {                           \
      v2f tmp = s[v];                                                          \
      s[v] = s[v | (1 << (T))];                                                \
      s[v | (1 << (T))] = tmp;                                                 \
    }                                                                          \
  } while (0)

// Window maps: 13-bit local index from (t[8:0], reg v[3:0]).
// Wave bits of the LDS address (c[12:10]) are INVARIANT (= tid[8:6]) for
// A2, A3, A4, B2, B3 -> remaps among those are wave-local (no barrier).
// Only A1 (wave = c[8:6]) crosses waves.
#define MAP_A1(t, v) (((v) << 9) | (t))                               // reg = bits 12..9
#define MAP_A2(t, v) ((((t) >> 6) << 10) | ((v) << 6) | ((t) & 63))   // reg = bits 9..6
#define MAP_A3(t, v) ((((t) >> 3) << 7) | ((v) << 3) | ((t) & 7))     // reg = bits 6..3
#define MAP_A4(t, v) (((t) << 4) | (v))                               // reg = bits 3..0
#define MAP_B2(t, v) ((((t) >> 2) << 6) | ((v) << 2) | ((t) & 3))     // reg = bits 5..2
#define MAP_B3(t, v) ((((t) >> 1) << 5) | ((v) << 1) | ((t) & 1))     // reg = bits 4..1

#define REMAP_W(MW)                                                            \
  _Pragma("unroll") for (int r = 0; r < NR; ++r) lds2[swz(MW(tid, r))] = s[r]
#define REMAP_R(MR)                                                            \
  _Pragma("unroll") for (int v = 0; v < NR; ++v) s[v] = lds2[swz(MR(tid, v))]

// Wave-local remap: no barriers (per-wave in-order DS + compiler lgkmcnt).
#define REMAP_L(MW, MR)  do { REMAP_W(MW); REMAP_R(MR); } while (0)
// Cross write (A1): all waves must finish reading before anyone writes A1.
#define REMAP_BWB(MW, MR) do { __syncthreads(); REMAP_W(MW); __syncthreads(); REMAP_R(MR); } while (0)
// Own-region write, then barrier, then cross read (A1).
#define REMAP_WB(MW, MR)  do { REMAP_W(MW); __syncthreads(); REMAP_R(MR); } while (0)

// ---------------------------------------------------------------------------
// Fused U = RZ @ RY @ RX per (layer, wire): (alpha_re, alpha_im, beta_re, beta_im)
__global__ void k_setup(const float* __restrict__ params, float4* __restrict__ Utab) {
  int g = threadIdx.x;
  if (g < 64) {
    float a = params[g * 3 + 0] * 0.5f;
    float b = params[g * 3 + 1] * 0.5f;
    float c = params[g * 3 + 2] * 0.5f;
    float sa, ca, sb, cb, sc, cc;
    sincosf(a, &sa, &ca);
    sincosf(b, &sb, &cb);
    sincosf(c, &sc, &cc);
    float X = cb * ca, Y = sb * sa;
    float Xp = -sb * ca, Yp = -cb * sa;
    Utab[g] = make_float4(cc * X + sc * Y, cc * Y - sc * X,
                          cc * Xp + sc * Yp, cc * Yp - sc * Xp);
  }
}

// ---------------------------------------------------------------------------
// Pass A: local wires 0..12 (orig bits 15..3); wire q <-> local bit 12-q.
__global__ __launch_bounds__(NT, 2) void k_passA(const float* __restrict__ in,
                                                 const float4* __restrict__ Utab,
                                                 v2f* __restrict__ st) {
  __shared__ v2f lds2[8192];
  const int tid = threadIdx.x;
  const int g = (blockIdx.x >> 3) & 7;
  const int b = ((blockIdx.x >> 6) << 3) | (blockIdx.x & 7);
  const float* base = in + (size_t)b * 65536;

  v2f s[NR];
#pragma unroll
  for (int v = 0; v < NR; ++v) {
    float re = base[(v << 12) + (tid << 3) + g];
    s[v] = v2f{re, 0.0f};
  }

#pragma unroll
  for (int l = 0; l < 4; ++l) {
    // W1: reg bits 12..9 = wires 0..3 (T = 3-q)
    ROT(3, l * 16 + 0); ROT(2, l * 16 + 1); ROT(1, l * 16 + 2); ROT(0, l * 16 + 3);
    CNOTW(3, 2); CNOTW(2, 1); CNOTW(1, 0);       // C_l (0,1),(1,2),(2,3)
    REMAP_BWB(MAP_A1, MAP_A2);                   // cross write, cross sync
    // W2: reg bits 9..6 = wires 3..6; rotations on 4,5,6 (T = 6-q)
    ROT(2, l * 16 + 4); ROT(1, l * 16 + 5); ROT(0, l * 16 + 6);
    CNOTW(3, 2); CNOTW(2, 1); CNOTW(1, 0);       // C_l (3,4),(4,5),(5,6)
    REMAP_L(MAP_A2, MAP_A3);                     // wave-local
    // W3: reg bits 6..3 = wires 6..9; rotations on 7,8,9 (T = 9-q)
    ROT(2, l * 16 + 7); ROT(1, l * 16 + 8); ROT(0, l * 16 + 9);
    CNOTW(3, 2); CNOTW(2, 1); CNOTW(1, 0);       // C_l (6,7),(7,8),(8,9)
    if (l < 3) {
      REMAP_L(MAP_A3, MAP_A4);                   // wave-local
      // W4: reg bits 3..0 = wires 9..12 (T = 12-q); staircase tail
      ROT(2, l * 16 + 10);
      if (l <= 1) ROT(1, l * 16 + 11);
      if (l == 0) ROT(0, l * 16 + 12);
      CNOTW(3, 2);
      if (l <= 1) CNOTW(2, 1);
      if (l == 0) CNOTW(1, 0);
      REMAP_WB(MAP_A4, MAP_A1);                  // own write, barrier, cross read
    }
  }

  // Store bounce (from A3 arrangement, own-region write; linear read crosses).
  REMAP_W(MAP_A3);
  __syncthreads();
  float4* outp = (float4*)(st + (size_t)(b * 8 + g) * 8192);
#pragma unroll
  for (int k = 0; k < 8; ++k) {
    int o = (k << 10) + (tid << 1);
    v2f a0 = lds2[swz(o)], a1 = lds2[swz(o + 1)];
    outp[(k << 9) + tid] = make_float4(a0[0], a0[1], a1[0], a1[1]);
  }
}

// ---------------------------------------------------------------------------
// Pass B: local wires 3..15 (orig bits 12..0); wire q <-> local bit 15-q.
// Entry write and all remaps are wave-local (wave = c[12:10] throughout).
__global__ __launch_bounds__(NT, 2) void k_passB(const v2f* __restrict__ st,
                                                 const float4* __restrict__ Utab,
                                                 float* __restrict__ partials) {
  __shared__ v2f lds2[8192];
  const int tid = threadIdx.x;
  const int b = blockIdx.x >> 3;
  const int h = blockIdx.x & 7;  // orig bits 15..13
  const float4* base4 = (const float4*)(st + (size_t)b * 65536);

  // Coalesced float4 load; element i of chunk k has c = (i<<3)|k.
  // c bits 12..10 = tid[8:6] -> own-region write, no barrier needed.
#pragma unroll
  for (int k = 0; k < 8; ++k) {
    float4 val = base4[(k << 12) + (h << 9) + tid];
    int i = tid << 1;
    lds2[swz(((i) << 3) | k)] = v2f{val.x, val.y};
    lds2[swz(((i + 1) << 3) | k)] = v2f{val.z, val.w};
  }
  v2f s[NR];
  REMAP_R(MAP_A4);  // own-region read

  // P0: reg bits 3..0 (T = bit)
  ROT(2, 13); ROT(1, 14); ROT(0, 15);          // R0 wires 13,14,15
  CNOTW(3, 2); CNOTW(2, 1); CNOTW(1, 0);       // C0 (12,13),(13,14),(14,15)
  ROT(3, 28); ROT(2, 29); ROT(1, 30); ROT(0, 31);  // R1 wires 12..15
  REMAP_L(MAP_A4, MAP_A3);
  // P1: reg bits 6..3 (T = bit-3)
  CNOTW(1, 0);      // C1 (11,12)
  ROT(1, 43);       // R2 wire 11
  CNOTW(2, 1);      // C2 (10,11)
  ROT(2, 58);       // R3 wire 10
  CNOTW(3, 2);      // C3 (9,10)
  REMAP_L(MAP_A3, MAP_B2);
  // P2: reg bits 5..2 (T = bit-2)
  CNOTW(1, 0);      // C1 (12,13)
  ROT(1, 44);       // R2 wire 12
  CNOTW(2, 1);      // C2 (11,12)
  ROT(2, 59);       // R3 wire 11
  CNOTW(3, 2);      // C3 (10,11)
  REMAP_L(MAP_B2, MAP_B3);
  // P3: reg bits 4..1 (T = bit-1)
  CNOTW(1, 0);      // C1 (13,14)
  ROT(1, 45);       // R2 wire 13
  CNOTW(2, 1);      // C2 (12,13)
  ROT(2, 60);       // R3 wire 12
  CNOTW(3, 2);      // C3 (11,12)
  REMAP_L(MAP_B3, MAP_A4);
  // P4: reg bits 3..0 (T = bit)
  CNOTW(1, 0);                 // C1 (14,15)
  ROT(1, 46); ROT(0, 47);      // R2 wires 14,15
  CNOTW(2, 1); CNOTW(1, 0);    // C2 (13,14),(14,15)
  ROT(2, 61); ROT(1, 62); ROT(0, 63);  // R3 wires 13,14,15
  CNOTW(3, 2); CNOTW(2, 1); CNOTW(1, 0);  // C3 (12,13),(13,14),(14,15)

  // Epilogue (A4 arrangement): c = (t<<4)|v; v bits 3..0 = wires 12..15,
  // t bits 8..0 = wires 3..11 (wire q <-> t bit 11-q).
  float P = 0.f, f12 = 0.f, f13 = 0.f, f14 = 0.f, f15 = 0.f;
#pragma unroll
  for (int v = 0; v < NR; ++v) {
    float p = s[v][0] * s[v][0] + s[v][1] * s[v][1];
    P += p;
    f12 += ((v >> 3) & 1) ? -p : p;
    f13 += ((v >> 2) & 1) ? -p : p;
    f14 += ((v >> 1) & 1) ? -p : p;
    f15 += ((v >> 0) & 1) ? -p : p;
  }
  float vals[14];
  vals[0] = P;
#pragma unroll
  for (int q = 3; q <= 11; ++q)
    vals[q - 2] = ((tid >> (11 - q)) & 1) ? -P : P;
  vals[10] = f12; vals[11] = f13; vals[12] = f14; vals[13] = f15;

  const int lane = tid & 63, w = tid >> 6;
#pragma unroll
  for (int q = 0; q < 14; ++q) {
    float x = vals[q];
#pragma unroll
    for (int m = 1; m < 64; m <<= 1) x += __shfl_xor(x, m, 64);
    vals[q] = x;
  }
  // red[] lives in wave-0's LDS region -> must sync all waves' prior reads.
  __syncthreads();
  float* red = (float*)lds2;
  if (lane == 0) {
#pragma unroll
    for (int q = 0; q < 14; ++q) red[q * 8 + w] = vals[q];
  }
  __syncthreads();
  if (tid < 14) {
    float F = 0.f;
#pragma unroll
    for (int ww = 0; ww < 8; ++ww) F += red[tid * 8 + ww];
    float* pt = partials + (size_t)blockIdx.x * 16;
    if (tid == 0) {
      pt[0] = (h & 4) ? -F : F;  // wire 0 <-> h bit 2
      pt[1] = (h & 2) ? -F : F;  // wire 1
      pt[2] = (h & 1) ? -F : F;  // wire 2
    } else {
      pt[tid + 2] = F;           // tid 1..9 -> wires 3..11; 10..13 -> 12..15
    }
  }
}

// ---------------------------------------------------------------------------
__global__ void k_head(const float* __restrict__ partials, const float* __restrict__ w,
                       const float* __restrict__ bh, float* __restrict__ out) {
  int b = threadIdx.x;  // 256 threads
  float acc = bh[0];
  for (int q = 0; q < 16; ++q) {
    float F = 0.f;
    for (int hh = 0; hh < 8; ++hh) F += partials[(size_t)(b * 8 + hh) * 16 + q];
    acc += w[q] * F;
  }
  out[b] = acc;
}

// ---------------------------------------------------------------------------
extern "C" void kernel_launch(void* const* d_in, const int* in_sizes, int n_in,
                              void* d_out, int out_size, void* d_ws, size_t ws_size,
                              hipStream_t stream) {
  const float* state  = (const float*)d_in[0];
  const float* params = (const float*)d_in[1];
  const float* w_head = (const float*)d_in[2];
  const float* b_head = (const float*)d_in[3];
  float* out = (float*)d_out;

  char* ws = (char*)d_ws;
  v2f* st = (v2f*)ws;                                       // 128 MB
  float4* Utab = (float4*)(ws + (size_t)134217728);         // 1 KB
  float* partials = (float*)(ws + (size_t)134217728 + 1024);

  k_setup<<<1, 64, 0, stream>>>(params, Utab);
  k_passA<<<dim3(2048), dim3(NT), 0, stream>>>(state, Utab, st);
  k_passB<<<dim3(2048), dim3(NT), 0, stream>>>(st, Utab, partials);
  k_head<<<1, 256, 0, stream>>>(partials, w_head, b_head, out);
}

// Round 6
// 222.099 us; speedup vs baseline: 1.2496x; 1.1289x over previous
//
#include <hip/hip_runtime.h>

typedef float v2f __attribute__((ext_vector_type(2)));

#define NT 256   // threads per block
#define NR 16    // v2f amplitudes per thread (4-bit register window)

// ---------------------------------------------------------------------------
// LDS swizzle: l ^ ((l>>5)&31) -- measured ~free (2-way max) on all maps.
__device__ __forceinline__ int swz(int l) { return l ^ ((l >> 5) & 31); }

// SU(2) rotation on a register pair: U = [[a, b], [-conj(b), conj(a)]]
__device__ __forceinline__ void rot2(v2f& x, v2f& y, v2f aa, v2f an, v2f bb, v2f bn) {
  v2f xs = __builtin_shufflevector(x, x, 1, 0);
  v2f ys = __builtin_shufflevector(y, y, 1, 0);
  v2f n0 = aa * x + an * xs + bb * y + bn * ys;
  v2f n1 = aa * y - an * ys + bn * xs - bb * x;
  x = n0;
  y = n1;
}

#define ROT(T, G)                                                              \
  do {                                                                         \
    const float4 u = Utab[G];                                                  \
    const v2f aa = {u.x, u.x}, an = {-u.y, u.y};                               \
    const v2f bb = {u.z, u.z}, bn = {-u.w, u.w};                               \
    _Pragma("unroll") for (int v = 0; v < NR; ++v) if (!((v >> (T)) & 1))      \
        rot2(s[v], s[v | (1 << (T))], aa, an, bb, bn);                         \
  } while (0)

// CNOT (control C, target T reg-bits): compile-time register swap.
#define CNOTW(C, T)                                                            \
  do {                                                                         \
    _Pragma("unroll") for (int v = 0; v < NR; ++v)                             \
        if (((v >> (C)) & 1) && !((v >> (T)) & 1)) {                           \
      v2f tmp = s[v];                                                          \
      s[v] = s[v | (1 << (T))];                                                \
      s[v | (1 << (T))] = tmp;                                                 \
    }                                                                          \
  } while (0)

// Window maps: 12-bit local index c from (t[7:0], reg v[3:0]).
// Wave bits c11..10 = t7..6 for W2,W3,W4,B3,C4,D63 (wave-local);
// only W1 (c11..8 = v) crosses waves.
#define MAP_W1(t, v)  (((v) << 8) | (t))                               // reg = c11..8
#define MAP_W2(t, v)  ((((t) >> 5) << 9) | ((v) << 5) | ((t) & 31))    // reg = c8..5
#define MAP_W3(t, v)  ((((t) >> 2) << 6) | ((v) << 2) | ((t) & 3))     // reg = c5..2
#define MAP_W4(t, v)  (((t) << 4) | (v))                               // reg = c3..0
#define MAP_B3(t, v)  ((((t) >> 1) << 5) | ((v) << 1) | ((t) & 1))     // reg = c4..1
#define MAP_C4(t, v)  ((((t) >> 4) << 8) | ((v) << 4) | ((t) & 15))    // reg = c7..4
#define MAP_D63(t, v) ((((t) >> 3) << 7) | ((v) << 3) | ((t) & 7))     // reg = c6..3

#define REMAP_W(MW)                                                            \
  _Pragma("unroll") for (int r = 0; r < NR; ++r) lds2[swz(MW(tid, r))] = s[r]
#define REMAP_R(MR)                                                            \
  _Pragma("unroll") for (int v = 0; v < NR; ++v) s[v] = lds2[swz(MR(tid, v))]

// Wave-local remap: no barriers (per-wave in-order DS + compiler lgkmcnt).
#define REMAP_L(MW, MR)  do { REMAP_W(MW); REMAP_R(MR); } while (0)
// Cross-wave write (W1): barrier both sides.
#define REMAP_BWB(MW, MR) do { __syncthreads(); REMAP_W(MW); __syncthreads(); REMAP_R(MR); } while (0)
// Own-region write, barrier, cross-wave read (-> W1).
#define REMAP_WB(MW, MR)  do { REMAP_W(MW); __syncthreads(); REMAP_R(MR); } while (0)

// ---------------------------------------------------------------------------
// Fused U = RZ @ RY @ RX per (layer, wire): (alpha_re, alpha_im, beta_re, beta_im)
__global__ void k_setup(const float* __restrict__ params, float4* __restrict__ Utab) {
  int g = threadIdx.x;
  if (g < 64) {
    float a = params[g * 3 + 0] * 0.5f;
    float b = params[g * 3 + 1] * 0.5f;
    float c = params[g * 3 + 2] * 0.5f;
    float sa, ca, sb, cb, sc, cc;
    sincosf(a, &sa, &ca);
    sincosf(b, &sb, &cb);
    sincosf(c, &sc, &cc);
    float X = cb * ca, Y = sb * sa;
    float Xp = -sb * ca, Yp = -cb * sa;
    Utab[g] = make_float4(cc * X + sc * Y, cc * Y - sc * X,
                          cc * Xp + sc * Yp, cc * Yp - sc * Xp);
  }
}

// ---------------------------------------------------------------------------
// Pass A: local wires 0..11 (orig bits 15..4); wire q <-> local bit 11-q.
// Executes R_l(q <= 11-l), C_l(q,q+1) for q <= 10-l (staircase light-cone).
// Tile 4096 amps = 32 KB LDS; g = orig bits 3..0 (16 chunks/batch).
__global__ __launch_bounds__(NT, 4) void k_passA(const float* __restrict__ in,
                                                 const float4* __restrict__ Utab,
                                                 v2f* __restrict__ st) {
  __shared__ v2f lds2[4096];
  const int tid = threadIdx.x;
  // XCD grouping: all 16 g-siblings of batch b on one XCD, adjacent slots.
  const int xcd = blockIdx.x & 7;
  const int y = blockIdx.x >> 3;
  const int g = y & 15;
  const int b = xcd | ((y >> 4) << 3);
  const float* base = in + (size_t)b * 65536;

  v2f s[NR];
  // Direct load in W1 arrangement: orig = v<<12 | tid<<4 | g.
#pragma unroll
  for (int v = 0; v < NR; ++v) {
    float re = base[(v << 12) + (tid << 4) + g];
    s[v] = v2f{re, 0.0f};
  }

#pragma unroll
  for (int l = 0; l < 4; ++l) {
    // W1: reg c11..8 = wires 0..3 (T = 3-q)
    ROT(3, l * 16 + 0); ROT(2, l * 16 + 1); ROT(1, l * 16 + 2); ROT(0, l * 16 + 3);
    CNOTW(3, 2); CNOTW(2, 1); CNOTW(1, 0);       // C_l (0,1),(1,2),(2,3)
    REMAP_BWB(MAP_W1, MAP_W2);
    // W2: reg c8..5 = wires 3..6; rotations on 4,5,6 (T = 6-q)
    ROT(2, l * 16 + 4); ROT(1, l * 16 + 5); ROT(0, l * 16 + 6);
    CNOTW(3, 2); CNOTW(2, 1); CNOTW(1, 0);       // C_l (3,4),(4,5),(5,6)
    REMAP_L(MAP_W2, MAP_W3);
    // W3: reg c5..2 = wires 6..9 (T = 9-q); staircase trims l=2,3
    ROT(2, l * 16 + 7); ROT(1, l * 16 + 8);
    if (l <= 2) ROT(0, l * 16 + 9);
    CNOTW(3, 2); CNOTW(2, 1);                    // C_l (6,7),(7,8)
    if (l <= 2) CNOTW(1, 0);                     // C_l (8,9)
    if (l <= 1) {
      REMAP_L(MAP_W3, MAP_W4);
      // W4: reg c3..0 = wires 8..11 (T = 11-q); staircase tail
      if (l == 0) { ROT(1, 10); ROT(0, 11); CNOTW(2, 1); CNOTW(1, 0); }
      else        { ROT(1, 16 + 10); CNOTW(2, 1); }
      REMAP_WB(MAP_W4, MAP_W1);
    } else if (l == 2) {
      REMAP_WB(MAP_W3, MAP_W1);
    }
  }

  // Exit (arrangement W3): own-region write, barrier, linear coalesced reads.
  REMAP_W(MAP_W3);
  __syncthreads();
  v2f* outp = st + (size_t)(b * 16 + g) * 4096;
#pragma unroll
  for (int k = 0; k < 16; ++k) outp[(k << 8) + tid] = lds2[swz((k << 8) | tid)];
}

// ---------------------------------------------------------------------------
// Pass B: local wires 4..15 (orig bits 11..0); wire q <-> local bit 15-q.
// Executes R_l(q >= 12-l), C_l(q,q+1) for q >= 11-l. Active bits 7..0 only.
// All remaps wave-local (c11..10 = t7..6 throughout) -> barrier-free.
// h = orig bits 15..12 (16 blocks/batch).
__global__ __launch_bounds__(NT, 4) void k_passB(const v2f* __restrict__ st,
                                                 const float4* __restrict__ Utab,
                                                 float* __restrict__ partials) {
  __shared__ v2f lds2[4096];
  const int tid = threadIdx.x;
  const int b = blockIdx.x >> 4;
  const int h = blockIdx.x & 15;
  const v2f* base = st + (size_t)b * 65536;

  // Direct coalesced entry in W4 arrangement: amp c = tid<<4 | v lives in
  // chunk g = v at row h<<8 | tid.
  v2f s[NR];
#pragma unroll
  for (int v = 0; v < NR; ++v) s[v] = base[(size_t)v * 4096 + (h << 8) + tid];

  // pre (W4, bits 3..0): R0 wires 12..15 (T = 15-q)
  ROT(3, 12); ROT(2, 13); ROT(1, 14); ROT(0, 15);
  REMAP_L(MAP_W4, MAP_B3);
  // Q0 (bits 4..1, T = bit-1): C0 chain head + R1 high
  CNOTW(3, 2); CNOTW(2, 1); CNOTW(1, 0);        // C0 (11,12),(12,13),(13,14)
  ROT(3, 16 + 11); ROT(2, 16 + 12); ROT(1, 16 + 13);  // R1 w11,12,13
  REMAP_L(MAP_B3, MAP_W4);
  // Q1 (bits 3..0): chain tails
  CNOTW(1, 0);                                   // C0 (14,15)
  ROT(1, 16 + 14); ROT(0, 16 + 15);              // R1 w14,15
  REMAP_L(MAP_W4, MAP_C4);
  // D0 (bits 7..4, T = bit-4)
  CNOTW(1, 0);                                   // C1 (10,11)
  ROT(1, 32 + 10);                               // R2 w10
  CNOTW(2, 1);                                   // C2 (9,10)
  ROT(2, 48 + 9);                                // R3 w9
  CNOTW(3, 2);                                   // C3 (8,9)
  REMAP_L(MAP_C4, MAP_D63);
  // D1 (bits 6..3, T = bit-3)
  CNOTW(1, 0);                                   // C1 (11,12)
  ROT(1, 32 + 11);                               // R2 w11
  CNOTW(2, 1);                                   // C2 (10,11)
  ROT(2, 48 + 10);                               // R3 w10
  CNOTW(3, 2);                                   // C3 (9,10)
  REMAP_L(MAP_D63, MAP_W3);
  // D2 (bits 5..2, T = bit-2)
  CNOTW(1, 0);                                   // C1 (12,13)
  ROT(1, 32 + 12);                               // R2 w12
  CNOTW(2, 1);                                   // C2 (11,12)
  ROT(2, 48 + 11);                               // R3 w11
  CNOTW(3, 2);                                   // C3 (10,11)
  REMAP_L(MAP_W3, MAP_B3);
  // D3 (bits 4..1, T = bit-1)
  CNOTW(1, 0);                                   // C1 (13,14)
  ROT(1, 32 + 13);                               // R2 w13
  CNOTW(2, 1);                                   // C2 (12,13)
  ROT(2, 48 + 12);                               // R3 w12
  CNOTW(3, 2);                                   // C3 (11,12)
  REMAP_L(MAP_B3, MAP_W4);
  // D4 (bits 3..0): chain tails
  CNOTW(1, 0);                                   // C1 (14,15)
  ROT(1, 32 + 14); ROT(0, 32 + 15);              // R2 w14,15
  CNOTW(2, 1); CNOTW(1, 0);                      // C2 (13,14),(14,15)
  ROT(2, 48 + 13); ROT(1, 48 + 14); ROT(0, 48 + 15);  // R3 w13,14,15
  CNOTW(3, 2); CNOTW(2, 1); CNOTW(1, 0);         // C3 (12,13),(13,14),(14,15)

  // Epilogue (W4 arrangement): c = t<<4|v; wires 12..15 <-> v3..0,
  // wires 4..11 <-> t7..0 (wire q <-> t bit 11-q), wires 0..3 <-> h bits 3..0.
  float P = 0.f, f12 = 0.f, f13 = 0.f, f14 = 0.f, f15 = 0.f;
#pragma unroll
  for (int v = 0; v < NR; ++v) {
    float p = s[v][0] * s[v][0] + s[v][1] * s[v][1];
    P += p;
    f12 += ((v >> 3) & 1) ? -p : p;
    f13 += ((v >> 2) & 1) ? -p : p;
    f14 += ((v >> 1) & 1) ? -p : p;
    f15 += ((v >> 0) & 1) ? -p : p;
  }
  float vals[13];
  vals[0] = P;
#pragma unroll
  for (int q = 4; q <= 11; ++q)
    vals[q - 3] = ((tid >> (11 - q)) & 1) ? -P : P;
  vals[9] = f12; vals[10] = f13; vals[11] = f14; vals[12] = f15;

  const int lane = tid & 63, w = tid >> 6;
#pragma unroll
  for (int q = 0; q < 13; ++q) {
    float x = vals[q];
#pragma unroll
    for (int m = 1; m < 64; m <<= 1) x += __shfl_xor(x, m, 64);
    vals[q] = x;
  }
  __syncthreads();  // red[] lives in wave-0's region
  float* red = (float*)lds2;
  if (lane == 0) {
#pragma unroll
    for (int q = 0; q < 13; ++q) red[q * 4 + w] = vals[q];
  }
  __syncthreads();
  if (tid < 13) {
    float F = 0.f;
#pragma unroll
    for (int ww = 0; ww < 4; ++ww) F += red[tid * 4 + ww];
    float* pt = partials + (size_t)blockIdx.x * 16;
    if (tid == 0) {
      pt[0] = (h & 8) ? -F : F;  // wire 0 <-> h bit 3
      pt[1] = (h & 4) ? -F : F;  // wire 1
      pt[2] = (h & 2) ? -F : F;  // wire 2
      pt[3] = (h & 1) ? -F : F;  // wire 3
    } else {
      pt[tid + 3] = F;           // tid 1..8 -> wires 4..11; 9..12 -> 12..15
    }
  }
}

// ---------------------------------------------------------------------------
__global__ void k_head(const float* __restrict__ partials, const float* __restrict__ w,
                       const float* __restrict__ bh, float* __restrict__ out) {
  int b = threadIdx.x;  // 256 threads
  float acc = bh[0];
  for (int q = 0; q < 16; ++q) {
    float F = 0.f;
    for (int hh = 0; hh < 16; ++hh) F += partials[(size_t)(b * 16 + hh) * 16 + q];
    acc += w[q] * F;
  }
  out[b] = acc;
}

// ---------------------------------------------------------------------------
extern "C" void kernel_launch(void* const* d_in, const int* in_sizes, int n_in,
                              void* d_out, int out_size, void* d_ws, size_t ws_size,
                              hipStream_t stream) {
  const float* state  = (const float*)d_in[0];
  const float* params = (const float*)d_in[1];
  const float* w_head = (const float*)d_in[2];
  const float* b_head = (const float*)d_in[3];
  float* out = (float*)d_out;

  char* ws = (char*)d_ws;
  v2f* st = (v2f*)ws;                                       // 128 MB
  float4* Utab = (float4*)(ws + (size_t)134217728);         // 1 KB
  float* partials = (float*)(ws + (size_t)134217728 + 1024);// 256 KB

  k_setup<<<1, 64, 0, stream>>>(params, Utab);
  k_passA<<<dim3(4096), dim3(NT), 0, stream>>>(state, Utab, st);
  k_passB<<<dim3(4096), dim3(NT), 0, stream>>>(st, Utab, partials);
  k_head<<<1, 256, 0, stream>>>(partials, w_head, b_head, out);
}